// Round 14
// baseline (177.389 us; speedup 1.0000x reference)
//
#include <hip/hip_runtime.h>

// HMM forward: alpha_t = (alpha_{t-1} @ A) * B[:, obs[t]]; out[t][s] = alpha_t[s].
// S=2048, T=8192, 512 symbols, fp32.
//
// alpha decays ~512x/step -> exact-zero underflow at t~17; after the first
// all-zero row every later row is zero (verified R1-R11). Honest recurrence +
// wave-local all-zero detection + tail zero-fill.
//
// R14 = R12 (wave-autonomous steps) with CHUNKED row consumption:
// Each of the 16 waves per block owns 2 output columns end-to-end. Lane l
// holds A[l+64k][j0,j0+1] (k=0..31) in registers. The wave consumes row t-1
// in 4 chunks of 8 encoded scalars: spin until the chunk is ready (epoch-bias
// check), decode+FMA immediately, next chunk. Values are stable once
// published, so incremental consumption is safe. This caps live inline-asm
// outputs at 8 (R12's 32 risked the 128-VGPR/lane ceiling at 1024 threads)
// and paces the poll traffic (R12 re-read all 32 per retry).
// After 4 chunks: 6-round shfl_xor tree -> full dot products in-wave; lane 0
// publishes 8B (sc1 ring + plain out). NO LDS partials, NO per-step
// __syncthreads, NO combine stage. Termination is wave-local: every wave
// reads the whole row -> identical all-zero verdict everywhere.
// Ring depth-2 induction (wave granularity): publishing row t+2 (slot t&1)
// requires consuming row t+1 -> every wave published row t+1 -> every wave
// fully consumed row t. No slot overwritten while readable.
// Epoch bias (R9-proven): row t -> slot t&1, bias (t>>1)&1 ? 0xC0000000 :
// 0x40000000; poison 0xAA../zeros/stale-epoch all read not-ready.
// A-hoist via LDS transpose (direct column loads = 16x line amplification,
// R4's disaster): 256 coalesced rows -> LDS (stride 33, conflict-free) ->
// registers; one-time, off-chain (step 0 published first).
// Fully data-dependent: would honestly run all 8191 steps if no underflow.

#define S     2048
#define T     8192
#define NSYM  512
#define NBLK  64
#define NTHR  1024
#define G     256          // staged A rows per transpose group
#define LSTR  33           // LDS floats per staged row (+1 pad: conflict-free)

typedef int v2i __attribute__((ext_vector_type(2)));

__device__ __forceinline__ void store_coherent_i2(int* p, v2i v) {
    // write-through to the agent coherence point (bypasses non-coherent L1/L2)
    asm volatile("global_store_dwordx2 %0, %1, off sc0 sc1"
                 :: "v"(p), "v"(v) : "memory");
}

// 4 coherent scalar loads from one base, stride 256B (64 floats), NO waitcnt.
#define POLLS4(e0,e1,e2,e3,bp)                                             \
    asm volatile("global_load_dword %0, %4, off sc0 sc1\n\t"               \
                 "global_load_dword %1, %4, off offset:256 sc0 sc1\n\t"    \
                 "global_load_dword %2, %4, off offset:512 sc0 sc1\n\t"    \
                 "global_load_dword %3, %4, off offset:768 sc0 sc1"        \
                 : "=&v"(e0), "=&v"(e1), "=&v"(e2), "=&v"(e3)              \
                 : "v"(bp) : "memory")

__global__ void __launch_bounds__(NTHR) hmm_fwd(
    const int*   __restrict__ obs,
    const float* __restrict__ A,
    const float* __restrict__ B,
    const float* __restrict__ pi,
    float*       __restrict__ out,
    int*         __restrict__ ring)    // d_ws: int ring[2][S] (no init needed)
{
    __shared__ float s_stage[G * LSTR];            // ~33.8 KB transpose buffer

    const int tx   = threadIdx.x;
    const int b    = blockIdx.x;
    const int lane = tx & 63;
    const int w    = tx >> 6;                      // wave id 0..15
    const int j0   = b * 32 + w * 2;               // this wave's 2 columns

    // ---- step 0 FIRST (off the serial chain): publish encoded alpha0 ----
    if (lane == 0) {
        const int o0 = obs[0];
        const float r0 = pi[j0]     * B[(size_t)j0       * NSYM + o0];
        const float r1 = pi[j0 + 1] * B[(size_t)(j0 + 1) * NSYM + o0];
        v2i e;
        e.x = (int)((unsigned)__float_as_int(r0) + 0x40000000u);
        e.y = (int)((unsigned)__float_as_int(r1) + 0x40000000u);
        store_coherent_i2(ring + j0, e);
        ((float2*)out)[j0 >> 1] = make_float2(r0, r1);   // plain, off-chain
    }

    // ---- A-hoist via LDS transpose: a0/a1[k] = A[lane+64k][j0 / j0+1] ----
    float a0[32], a1[32];
    const float4* A4 = (const float4*)A;
    #pragma unroll 1
    for (int g = 0; g < S / G; ++g) {
        __syncthreads();                           // guard LDS reuse
        #pragma unroll
        for (int i = 0; i < (G * 8) / NTHR; ++i) { // 2 f4/thread, coalesced
            const int idx = tx + i * NTHR;
            const int row = idx >> 3, f = idx & 7; // block cols = one 128B line/row
            const float4 v = A4[(size_t)(g * G + row) * (S / 4) + b * 8 + f];
            float* d = &s_stage[row * LSTR + f * 4];
            d[0] = v.x; d[1] = v.y; d[2] = v.z; d[3] = v.w;
        }
        __syncthreads();
        #pragma unroll
        for (int j = 0; j < G / 64; ++j) {         // 4 of this lane's rows here
            const int k  = g * (G / 64) + j;       // global row = lane + 64k
            const int lr = lane + 64 * j;
            a0[k] = s_stage[lr * LSTR + 2 * w];
            a1[k] = s_stage[lr * LSTR + 2 * w + 1];
        }
    }

    int fz = T;                                    // first row needing fill

    for (int t = 1; t < T; ++t) {
        // emission operands (plain loads, cached, consumed well after issue)
        const int   o   = obs[t];
        const float em0 = B[(size_t)j0       * NSYM + o];
        const float em1 = B[(size_t)(j0 + 1) * NSYM + o];

        const unsigned bp = (((t - 1) >> 1) & 1) ? 0xC0000000u : 0x40000000u;
        const int* base = ring + ((t - 1) & 1) * S + lane;

        float acc0 = 0.f, acc1 = 0.f;
        int nz = 0;

        // ---- consume row t-1 in 4 chunks of 8 scalars (k = 8c .. 8c+7) ----
        #pragma unroll 1
        for (int c = 0; c < 4; ++c) {
            const int* bq = base + c * 512;        // element lane + 64*(8c)
            int e0, e1, e2, e3, e4, e5, e6, e7;
            for (;;) {
                POLLS4(e0, e1, e2, e3, bq);
                POLLS4(e4, e5, e6, e7, bq + 256);
                asm volatile("s_waitcnt vmcnt(0)" ::: "memory");
                bool ok = true;
                ok &= ((unsigned)((unsigned)e0 - bp) <= 0x3F800000u);
                ok &= ((unsigned)((unsigned)e1 - bp) <= 0x3F800000u);
                ok &= ((unsigned)((unsigned)e2 - bp) <= 0x3F800000u);
                ok &= ((unsigned)((unsigned)e3 - bp) <= 0x3F800000u);
                ok &= ((unsigned)((unsigned)e4 - bp) <= 0x3F800000u);
                ok &= ((unsigned)((unsigned)e5 - bp) <= 0x3F800000u);
                ok &= ((unsigned)((unsigned)e6 - bp) <= 0x3F800000u);
                ok &= ((unsigned)((unsigned)e7 - bp) <= 0x3F800000u);
                if (ok) break;
            }
            // decode + FMA immediately (values are stable once published)
            #define TERM(E, R)                                                 \
                { const int d = (int)((unsigned)(E) - bp); nz |= d;            \
                  const float af = __int_as_float(d);                          \
                  acc0 = fmaf(af, a0[c * 8 + (R)], acc0);                      \
                  acc1 = fmaf(af, a1[c * 8 + (R)], acc1); }
            TERM(e0, 0) TERM(e1, 1) TERM(e2, 2) TERM(e3, 3)
            TERM(e4, 4) TERM(e5, 5) TERM(e6, 6) TERM(e7, 7)
            #undef TERM
        }

        #pragma unroll
        for (int m = 1; m <= 32; m <<= 1) {        // full 64-lane xor tree
            acc0 += __shfl_xor(acc0, m);
            acc1 += __shfl_xor(acc1, m);
        }

        if (__ballot(nz != 0) == 0ull) { fz = t; break; }  // row t-1 all zero

        // ---- publish row t: 8B sc1 to ring + plain out (lane 0) ----
        const float r0 = acc0 * em0, r1 = acc1 * em1;
        if (lane == 0) {
            const unsigned bt = ((t >> 1) & 1) ? 0xC0000000u : 0x40000000u;
            v2i en;
            en.x = (int)((unsigned)__float_as_int(r0) + bt);
            en.y = (int)((unsigned)__float_as_int(r1) + bt);
            store_coherent_i2(ring + (t & 1) * S + j0, en);
            ((float2*)(out + (size_t)t * S))[j0 >> 1] = make_float2(r0, r1);
        }
        // self-stale reads of our own slot heal via retry (epoch mismatch).
    }

    // all waves break at the same t (each saw the same all-zero row)
    __syncthreads();

    // ---- tail zero-fill: rows fz..T-1 (plain stores, R8-proven) ----
    {
        const size_t beg4 = (size_t)fz * (S / 4);
        const size_t end4 = (size_t)T * (S / 4);
        const float4 z = make_float4(0.f, 0.f, 0.f, 0.f);
        float4* o4 = (float4*)out;
        for (size_t i = beg4 + (size_t)b * NTHR + tx; i < end4;
             i += (size_t)NBLK * NTHR)
            o4[i] = z;
    }
}

extern "C" void kernel_launch(void* const* d_in, const int* in_sizes, int n_in,
                              void* d_out, int out_size, void* d_ws, size_t ws_size,
                              hipStream_t stream) {
    const int*   obs = (const int*)d_in[0];
    const float* A   = (const float*)d_in[1];
    const float* B   = (const float*)d_in[2];
    const float* pi  = (const float*)d_in[3];
    float* out = (float*)d_out;
    int* ring  = (int*)d_ws;           // 2*S ints = 16 KB

    // No memset: ring readiness is the epoch bias (0xAA poison / stale-epoch
    // values all read not-ready). No stop flags, no cooperative launch.
    hmm_fwd<<<dim3(NBLK), dim3(NTHR), 0, stream>>>(obs, A, B, pi, out, ring);
}

// Round 15
// 136.349 us; speedup vs baseline: 1.3010x; 1.3010x over previous
//
#include <hip/hip_runtime.h>

// HMM forward: alpha_t = (alpha_{t-1} @ A) * B[:, obs[t]]; out[t][s] = alpha_t[s].
// S=2048, T=8192, 512 symbols, fp32.
//
// alpha decays ~512x/step -> exact-zero underflow at t~17; after the first
// all-zero row every later row is zero (verified R1-R14, absmax 1e-38).
//
// R15 = R8 (best measured: 57us dispatch / 130us total) + one independent
// tweak: step-0 publish moved BEFORE the A register hoist (publish latency
// overlaps the hoist). R8's structure, proven over R9-R14 alternatives:
//  - 64 blocks x 32 contiguous cols: one 128B TCC line per A row per block
//    -> A L2-resident (FETCH 10MB, R5).
//  - block's A slice register-resident: lane holds 16 step-invariant float4
//    (R8: removed 256KB/step L2 A-feed).
//  - rows published ENCODED to out: enc = bits(a)+2^30 in [0x4000_0000,
//    0x7F80_0000] (alpha in [0,1]); poison 0xAA../zeros/stale-decoded all
//    read not-ready -> data-poll IS the barrier, one visibility hop/step.
//  - each wave polls 16 scalars (8 lanes/address -> coalesced broadcast),
//    row read ONCE per block (R14 ERROR: per-wave full-row reads = 16x MALL
//    traffic, 2x slower). shfl-reduce + ONE barrier + wave0 combine/publish.
//  - post-loop: 64-flag rendezvous, in-place decode, tail zero-fill (fill is
//    HBM-write-bound ~15us; speculative/256-block variants were net-zero).
// Fully data-dependent: would honestly run all 8191 steps if no underflow.

#define S     2048
#define T     8192
#define NSYM  512
#define NBLK  64
#define NTHR  1024
#define READY 0x40000000

typedef int v4i __attribute__((ext_vector_type(4)));

__device__ __forceinline__ v4i load_coherent_i4(const int* p) {
    v4i r;
    asm volatile("global_load_dwordx4 %0, %1, off sc0 sc1\n\ts_waitcnt vmcnt(0)"
                 : "=v"(r) : "v"(p) : "memory");
    return r;
}
__device__ __forceinline__ void store_coherent_i4(int* p, v4i v) {
    asm volatile("global_store_dwordx4 %0, %1, off sc0 sc1"
                 :: "v"(p), "v"(v) : "memory");
}

// 4 coherent scalar loads from one base (+0,+32,+64,+96 bytes), NO waitcnt.
#define POLL4(e0,e1,e2,e3,bp)                                              \
    asm volatile("global_load_dword %0, %4, off sc0 sc1\n\t"               \
                 "global_load_dword %1, %4, off offset:32 sc0 sc1\n\t"     \
                 "global_load_dword %2, %4, off offset:64 sc0 sc1\n\t"     \
                 "global_load_dword %3, %4, off offset:96 sc0 sc1"         \
                 : "=&v"(e0), "=&v"(e1), "=&v"(e2), "=&v"(e3)              \
                 : "v"(bp) : "memory")

__global__ void __launch_bounds__(NTHR) hmm_fwd(
    const int*   __restrict__ obs,
    const float* __restrict__ A,
    const float* __restrict__ B,
    const float* __restrict__ pi,
    float*       __restrict__ out,
    unsigned*    __restrict__ flag)      // 64 words, memset 0: post-loop rendezvous
{
    __shared__ float4 s_wpart[16][8];    // 2 KB per-wave partials
    __shared__ int    s_nz[4];           // depth-4 parity "row nonzero"

    const int tx   = threadIdx.x;
    const int b    = blockIdx.x;
    const int lane = tx & 63;
    const int w    = tx >> 6;            // wave id 0..15
    const int jl4  = lane & 7;           // col float4 within block (0..7)
    const int r_l  = lane >> 3;          // row-within-group (0..7)
    const int col4 = b * 8 + jl4;        // float4 column index (row = 512 float4)
    const float4* A4 = (const float4*)A;

    // ---- step 0 FIRST (publish overlaps the hoist below) ----
    if (tx < 8) {
        const int o0 = obs[0];
        const int j  = b * 32 + tx * 4;
        v4i e;
        e.x = __float_as_int(pi[j + 0] * B[(size_t)(j + 0) * NSYM + o0]) + READY;
        e.y = __float_as_int(pi[j + 1] * B[(size_t)(j + 1) * NSYM + o0]) + READY;
        e.z = __float_as_int(pi[j + 2] * B[(size_t)(j + 2) * NSYM + o0]) + READY;
        e.w = __float_as_int(pi[j + 3] * B[(size_t)(j + 3) * NSYM + o0]) + READY;
        store_coherent_i4((int*)out + j, e);
    }
    if (tx == 0) { s_nz[0] = 0; s_nz[1] = 0; s_nz[2] = 0; s_nz[3] = 0; }

    // ---- hoist the block's A slice into registers: a[q][s] = A4[i][col4],
    //      i = (w+16q)*32 + s*8 + r_l  (step-invariant) ----
    float4 a_reg[4][4];
    #pragma unroll
    for (int q = 0; q < 4; ++q)
        #pragma unroll
        for (int s = 0; s < 4; ++s) {
            const int i = (w + 16 * q) * 32 + s * 8 + r_l;
            a_reg[q][s] = A4[(size_t)i * (S / 4) + col4];
        }
    __syncthreads();

    int lastRow = T - 1;

    for (int t = 1; t < T; ++t) {
        // ---- emission prefetch (wave0 lanes; same lanes publish later) ----
        float em0 = 0.f, em1 = 0.f, em2 = 0.f, em3 = 0.f;
        if (tx < 8) {
            const int o = obs[t];
            const int j = b * 32 + tx * 4;
            em0 = B[(size_t)(j + 0) * NSYM + o];
            em1 = B[(size_t)(j + 1) * NSYM + o];
            em2 = B[(size_t)(j + 2) * NSYM + o];
            em3 = B[(size_t)(j + 3) * NSYM + o];
        }

        // ---- batch-poll this wave's 16 encoded alpha scalars of row t-1 ----
        const int* rb = (const int*)(out + (size_t)(t - 1) * S) + r_l;
        const int* b0 = rb + (w +  0) * 32;
        const int* b1 = rb + (w + 16) * 32;
        const int* b2 = rb + (w + 32) * 32;
        const int* b3 = rb + (w + 48) * 32;
        int e00, e01, e02, e03, e10, e11, e12, e13;
        int e20, e21, e22, e23, e30, e31, e32, e33;
        for (;;) {
            POLL4(e00, e01, e02, e03, b0);
            POLL4(e10, e11, e12, e13, b1);
            POLL4(e20, e21, e22, e23, b2);
            POLL4(e30, e31, e32, e33, b3);
            asm volatile("s_waitcnt vmcnt(0)" ::: "memory");
            const int m0 = (e00 < READY) | (e01 < READY) | (e02 < READY) | (e03 < READY);
            const int m1 = (e10 < READY) | (e11 < READY) | (e12 < READY) | (e13 < READY);
            const int m2 = (e20 < READY) | (e21 < READY) | (e22 < READY) | (e23 < READY);
            const int m3 = (e30 < READY) | (e31 < READY) | (e32 < READY) | (e33 < READY);
            if (!(m0 | m1 | m2 | m3)) break;
        }

        // ---- decode + FMA vs register-resident A ----
        float4 acc = make_float4(0.f, 0.f, 0.f, 0.f);
        int nzacc = 0;
        #define STEP1(E, Q, Ss)                                                \
            { const int d = (E) - READY; nzacc |= d;                           \
              const float af = __int_as_float(d);                              \
              acc.x = fmaf(af, a_reg[Q][Ss].x, acc.x);                         \
              acc.y = fmaf(af, a_reg[Q][Ss].y, acc.y);                         \
              acc.z = fmaf(af, a_reg[Q][Ss].z, acc.z);                         \
              acc.w = fmaf(af, a_reg[Q][Ss].w, acc.w); }
        STEP1(e00,0,0) STEP1(e01,0,1) STEP1(e02,0,2) STEP1(e03,0,3)
        STEP1(e10,1,0) STEP1(e11,1,1) STEP1(e12,1,2) STEP1(e13,1,3)
        STEP1(e20,2,0) STEP1(e21,2,1) STEP1(e22,2,2) STEP1(e23,2,3)
        STEP1(e30,3,0) STEP1(e31,3,1) STEP1(e32,3,2) STEP1(e33,3,3)
        #undef STEP1

        // in-wave reduce over lane bits 3,4,5 (the 8 r_l groups)
        #pragma unroll
        for (int m = 8; m <= 32; m <<= 1) {
            acc.x += __shfl_xor(acc.x, m);
            acc.y += __shfl_xor(acc.y, m);
            acc.z += __shfl_xor(acc.z, m);
            acc.w += __shfl_xor(acc.w, m);
        }
        if (lane < 8) s_wpart[w][lane] = acc;
        const unsigned long long nzm = __ballot(nzacc != 0);
        if (nzm != 0ull && lane == 0) s_nz[t & 3] = 1;   // benign same-value race
        if (tx == 0) s_nz[(t + 2) & 3] = 0;              // prep 2 steps ahead
        __syncthreads();                                 // the ONLY per-step barrier

        if (s_nz[t & 3] == 0) { lastRow = t - 1; break; }   // uniform everywhere

        // ---- wave0: combine 16 wave-partials, emission-multiply, publish ----
        if (tx < 64) {
            const int h = tx >> 3, c = tx & 7;
            float4 p = s_wpart[h][c];
            const float4 q4 = s_wpart[h + 8][c];
            p.x += q4.x; p.y += q4.y; p.z += q4.z; p.w += q4.w;
            #pragma unroll
            for (int m = 8; m <= 32; m <<= 1) {
                p.x += __shfl_xor(p.x, m);
                p.y += __shfl_xor(p.y, m);
                p.z += __shfl_xor(p.z, m);
                p.w += __shfl_xor(p.w, m);
            }
            if (tx < 8) {
                v4i e;
                e.x = __float_as_int(p.x * em0) + READY;
                e.y = __float_as_int(p.y * em1) + READY;
                e.z = __float_as_int(p.z * em2) + READY;
                e.w = __float_as_int(p.w * em3) + READY;
                store_coherent_i4((int*)(out + (size_t)t * S) + b * 32 + tx * 4, e);
            }
        }
        // no bottom barrier: next step's polls gate progress (R8-verified)
    }

    // ---- one-time rendezvous: nobody decodes rows still being poll-read ----
    if (tx == 0)
        __hip_atomic_store(&flag[b], 1u, __ATOMIC_RELAXED, __HIP_MEMORY_SCOPE_AGENT);
    if (tx < 64) {
        for (;;) {
            const unsigned f = __hip_atomic_load(&flag[tx], __ATOMIC_RELAXED,
                                                 __HIP_MEMORY_SCOPE_AGENT);
            if (__all(f == 1u)) break;
            __builtin_amdgcn_s_sleep(1);
        }
    }
    __syncthreads();

    // ---- decode own chunks of rows 0..lastRow in place ----
    for (int idx = tx; idx < (lastRow + 1) * 8; idx += NTHR) {
        const int r = idx >> 3, c = idx & 7;
        int* p = (int*)(out + (size_t)r * S) + b * 32 + c * 4;
        v4i e = load_coherent_i4(p);
        e.x -= READY; e.y -= READY; e.z -= READY; e.w -= READY;
        store_coherent_i4(p, e);
    }

    // ---- tail zero-fill: rows lastRow+1 .. T-1 ----
    {
        const size_t beg4 = (size_t)(lastRow + 1) * (S / 4);
        const size_t end4 = (size_t)T * (S / 4);
        const float4 z = make_float4(0.f, 0.f, 0.f, 0.f);
        float4* o4 = (float4*)out;
        for (size_t i = beg4 + (size_t)b * NTHR + tx; i < end4;
             i += (size_t)NBLK * NTHR)
            o4[i] = z;
    }
}

extern "C" void kernel_launch(void* const* d_in, const int* in_sizes, int n_in,
                              void* d_out, int out_size, void* d_ws, size_t ws_size,
                              hipStream_t stream) {
    const int*   obs = (const int*)d_in[0];
    const float* A   = (const float*)d_in[1];
    const float* B   = (const float*)d_in[2];
    const float* pi  = (const float*)d_in[3];
    float* out = (float*)d_out;
    unsigned* flag = (unsigned*)d_ws;

    // d_ws is poisoned before every launch; done-flags must start at 0.
    (void)hipMemsetAsync(d_ws, 0, (size_t)NBLK * sizeof(unsigned), stream);

    hmm_fwd<<<dim3(NBLK), dim3(NTHR), 0, stream>>>(obs, A, B, pi, out, flag);
}